// Round 1
// baseline (198.558 us; speedup 1.0000x reference)
//
#include <hip/hip_runtime.h>

typedef __attribute__((ext_vector_type(8))) __bf16 bf16x8;
typedef __attribute__((ext_vector_type(4))) float f32x4;
typedef __attribute__((ext_vector_type(4))) unsigned short us4;

__device__ __forceinline__ unsigned short f2bf(float f) {
  unsigned u = __builtin_bit_cast(unsigned, f);
  u = (u + 0x7FFFu + ((u >> 16) & 1u)) >> 16;
  return (unsigned short)u;
}

// Stage a [rows x 64] bf16 tile (row-major, row stride = ld elements in global)
// into LDS with 16B-chunk XOR swizzle: LDS(row, kc) = G(row, kc ^ (row&7)).
// Linear LDS dest (global_load_lds requirement); swizzle via per-lane global src.
__device__ __forceinline__ void stage_chunks(const unsigned short* g, int ld,
                                             unsigned short* lds, int rows, int tid) {
  int total = rows * 8;  // 16B chunks
  for (int c0 = 0; c0 < total; c0 += 256) {
    int c = c0 + tid;
    int row = c >> 3, kc = c & 7;
    const unsigned short* src = g + (size_t)row * ld + ((kc ^ (row & 7)) << 3);
    unsigned short* dst = lds + (size_t)(c0 + (tid & 192)) * 8;  // wave-uniform base
    __builtin_amdgcn_global_load_lds((const __attribute__((address_space(1))) void*)src,
                                     (__attribute__((address_space(3))) void*)dst,
                                     16, 0, 0);
  }
}

// Read one MFMA fragment (8 contiguous bf16 = 16B) from a swizzled [*x64] tile.
__device__ __forceinline__ bf16x8 frag(const unsigned short* lds, int row, int kc) {
  return *(const bf16x8*)(lds + row * 64 + ((kc ^ (row & 7)) << 3));
}

// ---------------- converts / transpose ----------------

__global__ void k_cvt(const float* __restrict__ in, unsigned short* __restrict__ outp, int n) {
  int i = (blockIdx.x * 256 + threadIdx.x) * 4;
  if (i + 3 < n) {
    f32x4 v = *(const f32x4*)(in + i);
    us4 o;
#pragma unroll
    for (int k = 0; k < 4; k++) o[k] = f2bf(v[k]);
    *(us4*)(outp + i) = o;
  }
}

// xT[b][n][c] = x[b][c][n], fp32 -> bf16
__global__ __launch_bounds__(256) void k_xpose(const float* __restrict__ x,
                                               unsigned short* __restrict__ xT) {
  __shared__ float t[32][33];
  int tid = threadIdx.x;
  int col = tid & 31, rowb = tid >> 5;
  int nt = blockIdx.x * 32, ct = blockIdx.y * 32, b = blockIdx.z;
  const float* src = x + ((size_t)b * 256 + ct) * 2304 + nt;
#pragma unroll
  for (int rr = 0; rr < 32; rr += 8) t[rowb + rr][col] = src[(size_t)(rowb + rr) * 2304 + col];
  __syncthreads();
  unsigned short* dst = xT + ((size_t)b * 2304 + nt) * 256 + ct;
#pragma unroll
  for (int rr = 0; rr < 32; rr += 8) dst[(size_t)(rowb + rr) * 256 + col] = f2bf(t[col][rowb + rr]);
}

// ---------------- GEMM1: qkv = Wqkv * x ----------------
// C[o][n] = sum_c W[o][c] * xT[n][c]; routes q,k -> transposed [bh][n][d], v -> [bh][d][n]
__global__ __launch_bounds__(256, 2) void k_gemm_qkv(
    const unsigned short* __restrict__ W, const unsigned short* __restrict__ xT,
    unsigned short* __restrict__ qT, unsigned short* __restrict__ kT,
    unsigned short* __restrict__ vv) {
  __shared__ unsigned short As[128 * 64];
  __shared__ unsigned short Bs[128 * 64];
  int tid = threadIdx.x, lane = tid & 63, wid = tid >> 6;
  int m0 = blockIdx.x * 128, n0 = blockIdx.y * 128, b = blockIdx.z;
  const unsigned short* Ag = W + (size_t)m0 * 256;
  const unsigned short* Bg = xT + ((size_t)b * 2304 + n0) * 256;
  int wm = (wid >> 1) * 64, wn = (wid & 1) * 64;
  f32x4 acc[4][4] = {};
  for (int kt = 0; kt < 256; kt += 64) {
    __syncthreads();
    stage_chunks(Ag + kt, 256, As, 128, tid);
    stage_chunks(Bg + kt, 256, Bs, 128, tid);
    __syncthreads();
#pragma unroll
    for (int kk = 0; kk < 2; kk++) {
      bf16x8 af[4], bf[4];
#pragma unroll
      for (int i = 0; i < 4; i++) af[i] = frag(As, wm + i * 16 + (lane & 15), kk * 4 + (lane >> 4));
#pragma unroll
      for (int j = 0; j < 4; j++) bf[j] = frag(Bs, wn + j * 16 + (lane & 15), kk * 4 + (lane >> 4));
#pragma unroll
      for (int i = 0; i < 4; i++)
#pragma unroll
        for (int j = 0; j < 4; j++)
          acc[i][j] = __builtin_amdgcn_mfma_f32_16x16x32_bf16(af[i], bf[j], acc[i][j], 0, 0, 0);
    }
  }
#pragma unroll
  for (int i = 0; i < 4; i++) {
    int o = m0 + wm + i * 16 + ((lane >> 4) << 2);
    int which = o >> 9, h = (o >> 6) & 7, d0 = o & 63;
#pragma unroll
    for (int j = 0; j < 4; j++) {
      int n = n0 + wn + j * 16 + (lane & 15);
      if (which == 2) {
#pragma unroll
        for (int jj = 0; jj < 4; jj++)
          vv[((size_t)(b * 8 + h) * 64 + d0 + jj) * 2304 + n] = f2bf(acc[i][j][jj]);
      } else {
        us4 pk;
#pragma unroll
        for (int jj = 0; jj < 4; jj++) pk[jj] = f2bf(acc[i][j][jj]);
        unsigned short* dst = (which ? kT : qT) + ((size_t)(b * 8 + h) * 2304 + n) * 64 + d0;
        *(us4*)dst = pk;
      }
    }
  }
}

// ---------------- flash attention ----------------
// per (bh, i-tile of 128): online softmax over j-tiles of 64.
// out2T[b][n][e] = attention output (e = h*64+d), bf16
__global__ __launch_bounds__(256, 2) void k_attn(
    const unsigned short* __restrict__ qT, const unsigned short* __restrict__ kT,
    const unsigned short* __restrict__ vv, unsigned short* __restrict__ o2T) {
  __shared__ unsigned short QP[128 * 64];  // Q tile, then reused per-wave as P
  __shared__ unsigned short Ks[64 * 64];
  __shared__ unsigned short Vs[64 * 64];
  int tid = threadIdx.x, lane = tid & 63, wid = tid >> 6;
  int i0 = blockIdx.x * 128, bh = blockIdx.y;
  stage_chunks(qT + ((size_t)bh * 2304 + i0) * 64, 64, QP, 128, tid);
  __syncthreads();
  bf16x8 qf[2][2];
#pragma unroll
  for (int mf = 0; mf < 2; mf++)
#pragma unroll
    for (int kk = 0; kk < 2; kk++)
      qf[mf][kk] = frag(QP, wid * 32 + mf * 16 + (lane & 15), kk * 4 + (lane >> 4));
  float mrun[8], lrun[8];
#pragma unroll
  for (int r = 0; r < 8; r++) { mrun[r] = -1e30f; lrun[r] = 0.f; }
  f32x4 O[2][4] = {};
  const float cs = 0.125f * 1.44269504088896f;  // scale * log2(e)
  for (int j0 = 0; j0 < 2304; j0 += 64) {
    __syncthreads();
    stage_chunks(kT + ((size_t)bh * 2304 + j0) * 64, 64, Ks, 64, tid);
    stage_chunks(vv + (size_t)bh * 64 * 2304 + j0, 2304, Vs, 64, tid);
    __syncthreads();
    f32x4 S[2][4] = {};
#pragma unroll
    for (int kk = 0; kk < 2; kk++) {
      bf16x8 kf[4];
#pragma unroll
      for (int nf = 0; nf < 4; nf++) kf[nf] = frag(Ks, nf * 16 + (lane & 15), kk * 4 + (lane >> 4));
#pragma unroll
      for (int mf = 0; mf < 2; mf++)
#pragma unroll
        for (int nf = 0; nf < 4; nf++)
          S[mf][nf] = __builtin_amdgcn_mfma_f32_16x16x32_bf16(qf[mf][kk], kf[nf], S[mf][nf], 0, 0, 0);
    }
#pragma unroll
    for (int mf = 0; mf < 2; mf++)
#pragma unroll
      for (int nf = 0; nf < 4; nf++) S[mf][nf] *= cs;
    float al[2][4];
#pragma unroll
    for (int mf = 0; mf < 2; mf++)
#pragma unroll
      for (int jj = 0; jj < 4; jj++) {
        float t = fmaxf(fmaxf(S[mf][0][jj], S[mf][1][jj]), fmaxf(S[mf][2][jj], S[mf][3][jj]));
#pragma unroll
        for (int msk = 1; msk < 16; msk <<= 1) t = fmaxf(t, __shfl_xor(t, msk));
        int r = mf * 4 + jj;
        float nm = fmaxf(mrun[r], t);
        float a = __builtin_amdgcn_exp2f(mrun[r] - nm);
        mrun[r] = nm; al[mf][jj] = a;
        float rs = 0.f;
#pragma unroll
        for (int nf = 0; nf < 4; nf++) {
          float p = __builtin_amdgcn_exp2f(S[mf][nf][jj] - nm);
          S[mf][nf][jj] = p; rs += p;
        }
#pragma unroll
        for (int msk = 1; msk < 16; msk <<= 1) rs += __shfl_xor(rs, msk);
        lrun[r] = lrun[r] * a + rs;
      }
#pragma unroll
    for (int mf = 0; mf < 2; mf++)
#pragma unroll
      for (int nf = 0; nf < 4; nf++)
#pragma unroll
        for (int jj = 0; jj < 4; jj++) O[mf][nf][jj] *= al[mf][jj];
    // write P (bf16) into per-wave-private rows of QP (swizzled)
#pragma unroll
    for (int mf = 0; mf < 2; mf++)
#pragma unroll
      for (int nf = 0; nf < 4; nf++)
#pragma unroll
        for (int jj = 0; jj < 4; jj++) {
          int row = wid * 32 + mf * 16 + ((lane >> 4) << 2) + jj;
          int col = nf * 16 + (lane & 15);
          QP[row * 64 + (((col >> 3) ^ (row & 7)) << 3) + (col & 7)] = f2bf(S[mf][nf][jj]);
        }
    // PV
#pragma unroll
    for (int kk = 0; kk < 2; kk++) {
      bf16x8 pf[2], vf[4];
#pragma unroll
      for (int mf = 0; mf < 2; mf++)
        pf[mf] = frag(QP, wid * 32 + mf * 16 + (lane & 15), kk * 4 + (lane >> 4));
#pragma unroll
      for (int nf = 0; nf < 4; nf++)
        vf[nf] = frag(Vs, nf * 16 + (lane & 15), kk * 4 + (lane >> 4));
#pragma unroll
      for (int mf = 0; mf < 2; mf++)
#pragma unroll
        for (int nf = 0; nf < 4; nf++)
          O[mf][nf] = __builtin_amdgcn_mfma_f32_16x16x32_bf16(pf[mf], vf[nf], O[mf][nf], 0, 0, 0);
    }
  }
  int b = bh >> 3, h = bh & 7;
#pragma unroll
  for (int mf = 0; mf < 2; mf++)
#pragma unroll
    for (int nf = 0; nf < 4; nf++)
#pragma unroll
      for (int jj = 0; jj < 4; jj++) {
        int r = mf * 4 + jj;
        int i = i0 + wid * 32 + mf * 16 + ((lane >> 4) << 2) + jj;
        int e = h * 64 + nf * 16 + (lane & 15);
        o2T[((size_t)b * 2304 + i) * 512 + e] = f2bf(O[mf][nf][jj] / lrun[r]);
      }
}

// ---------------- GEMM2: out = Wout * out2 + bout ----------------
__global__ __launch_bounds__(256, 2) void k_gemm_out(
    const unsigned short* __restrict__ Wo, const unsigned short* __restrict__ o2T,
    const float* __restrict__ bout, float* __restrict__ out) {
  __shared__ unsigned short As[128 * 64];
  __shared__ unsigned short Bs[128 * 64];
  int tid = threadIdx.x, lane = tid & 63, wid = tid >> 6;
  int m0 = blockIdx.x * 128, n0 = blockIdx.y * 128, b = blockIdx.z;
  const unsigned short* Ag = Wo + (size_t)m0 * 512;
  const unsigned short* Bg = o2T + ((size_t)b * 2304 + n0) * 512;
  int wm = (wid >> 1) * 64, wn = (wid & 1) * 64;
  f32x4 acc[4][4] = {};
  for (int kt = 0; kt < 512; kt += 64) {
    __syncthreads();
    stage_chunks(Ag + kt, 512, As, 128, tid);
    stage_chunks(Bg + kt, 512, Bs, 128, tid);
    __syncthreads();
#pragma unroll
    for (int kk = 0; kk < 2; kk++) {
      bf16x8 af[4], bf[4];
#pragma unroll
      for (int i = 0; i < 4; i++) af[i] = frag(As, wm + i * 16 + (lane & 15), kk * 4 + (lane >> 4));
#pragma unroll
      for (int j = 0; j < 4; j++) bf[j] = frag(Bs, wn + j * 16 + (lane & 15), kk * 4 + (lane >> 4));
#pragma unroll
      for (int i = 0; i < 4; i++)
#pragma unroll
        for (int j = 0; j < 4; j++)
          acc[i][j] = __builtin_amdgcn_mfma_f32_16x16x32_bf16(af[i], bf[j], acc[i][j], 0, 0, 0);
    }
  }
#pragma unroll
  for (int i = 0; i < 4; i++) {
    int c = m0 + wm + i * 16 + ((lane >> 4) << 2);
#pragma unroll
    for (int j = 0; j < 4; j++) {
      int n = n0 + wn + j * 16 + (lane & 15);
#pragma unroll
      for (int jj = 0; jj < 4; jj++)
        out[((size_t)b * 256 + c + jj) * 2304 + n] = acc[i][j][jj] + bout[c + jj];
    }
  }
}

extern "C" void kernel_launch(void* const* d_in, const int* in_sizes, int n_in,
                              void* d_out, int out_size, void* d_ws, size_t ws_size,
                              hipStream_t stream) {
  const float* x = (const float*)d_in[0];
  const float* Wqkv = (const float*)d_in[1];
  const float* Wout = (const float*)d_in[2];
  const float* bout = (const float*)d_in[3];
  float* out = (float*)d_out;
  char* ws = (char*)d_ws;
  // workspace layout (bytes)
  unsigned short* Wqkv_bf = (unsigned short*)(ws + 0);          //  786432
  unsigned short* Wout_bf = (unsigned short*)(ws + 786432);     //  262144
  unsigned short* xT      = (unsigned short*)(ws + 1048576);    // 4718592
  unsigned short* qT      = (unsigned short*)(ws + 5767168);    // 9437184
  unsigned short* kT      = (unsigned short*)(ws + 15204352);   // 9437184
  unsigned short* vv      = (unsigned short*)(ws + 24641536);   // 9437184
  unsigned short* o2T     = (unsigned short*)(ws + 34078720);   // 9437184 (end 43515904)

  k_cvt<<<dim3(384), dim3(256), 0, stream>>>(Wqkv, Wqkv_bf, 1536 * 256);
  k_cvt<<<dim3(128), dim3(256), 0, stream>>>(Wout, Wout_bf, 256 * 512);
  k_xpose<<<dim3(72, 8, 4), dim3(256), 0, stream>>>(x, xT);
  k_gemm_qkv<<<dim3(12, 18, 4), dim3(256), 0, stream>>>(Wqkv_bf, xT, qT, kT, vv);
  k_attn<<<dim3(18, 32), dim3(256), 0, stream>>>(qT, kT, vv, o2T);
  k_gemm_out<<<dim3(2, 18, 4), dim3(256), 0, stream>>>(Wout_bf, o2T, bout, out);
}